// Round 1
// baseline (256.470 us; speedup 1.0000x reference)
//
#include <hip/hip_runtime.h>

// Problem constants (from reference): B=4, C_RGB=64, C_EV=32, H=W=256, K=3, MID=32
#define CRGB 64
#define CEV  32
#define CIN  96
#define MID  32
#define HH   256
#define WW   256
#define HW   (HH * WW)

__global__ __launch_bounds__(256, 4) void fusion_kernel(
    const float* __restrict__ rgb, const float* __restrict__ ev,
    const float* __restrict__ W1, const float* __restrict__ b1,
    const float* __restrict__ W2, const float* __restrict__ b2,
    float* __restrict__ out)
{
    const int w = threadIdx.x;          // 0..255
    const int h = blockIdx.x & (HH - 1);
    const int b = blockIdx.x >> 8;

    const int hw = h * WW + w;
    const long baseRgb = (long)b * CRGB * HW;
    const long baseEv  = (long)b * CEV  * HW;

    // ---------------- conv1: hm[m] = relu(sum_c fused[c]*W1[m][c] + b1[m]) ----------
    float hm[MID];
#pragma unroll
    for (int m = 0; m < MID; ++m) hm[m] = 0.f;

    // rgb channels 0..63
    for (int c = 0; c < CRGB; c += 4) {
        const float x0 = rgb[baseRgb + (long)(c + 0) * HW + hw];
        const float x1 = rgb[baseRgb + (long)(c + 1) * HW + hw];
        const float x2 = rgb[baseRgb + (long)(c + 2) * HW + hw];
        const float x3 = rgb[baseRgb + (long)(c + 3) * HW + hw];
#pragma unroll
        for (int m = 0; m < MID; ++m) {
            const float4 wv = *(const float4*)(&W1[m * CIN + c]);
            hm[m] = fmaf(x0, wv.x, fmaf(x1, wv.y, fmaf(x2, wv.z, fmaf(x3, wv.w, hm[m]))));
        }
    }
    // event channels 64..95
    for (int c = 0; c < CEV; c += 4) {
        const float x0 = ev[baseEv + (long)(c + 0) * HW + hw];
        const float x1 = ev[baseEv + (long)(c + 1) * HW + hw];
        const float x2 = ev[baseEv + (long)(c + 2) * HW + hw];
        const float x3 = ev[baseEv + (long)(c + 3) * HW + hw];
#pragma unroll
        for (int m = 0; m < MID; ++m) {
            const float4 wv = *(const float4*)(&W1[m * CIN + CRGB + c]);
            hm[m] = fmaf(x0, wv.x, fmaf(x1, wv.y, fmaf(x2, wv.z, fmaf(x3, wv.w, hm[m]))));
        }
    }

#pragma unroll
    for (int m = 0; m < MID; ++m) {
        const float v = hm[m] + b1[m];
        hm[m] = v > 0.f ? v : 0.f;
    }

    // ---------------- reflect indices (pad=1) ----------------
    const int hm1 = (h == 0)      ? 1      : h - 1;
    const int hp1 = (h == HH - 1) ? HH - 2 : h + 1;
    const int wm1 = (w == 0)      ? 1      : w - 1;
    const int wp1 = (w == WW - 1) ? WW - 2 : w + 1;

    // ---------------- per output channel: dk = W2 @ hm + b2; out = <patch, dk> ------
    for (int co = 0; co < CRGB; ++co) {
        const float* plane = rgb + baseRgb + (long)co * HW;
        float p[9];
        p[0] = plane[hm1 * WW + wm1];
        p[1] = plane[hm1 * WW + w  ];
        p[2] = plane[hm1 * WW + wp1];
        p[3] = plane[h   * WW + wm1];
        p[4] = plane[h   * WW + w  ];
        p[5] = plane[h   * WW + wp1];
        p[6] = plane[hp1 * WW + wm1];
        p[7] = plane[hp1 * WW + w  ];
        p[8] = plane[hp1 * WW + wp1];

        float acc = 0.f;
#pragma unroll
        for (int ij = 0; ij < 9; ++ij) {
            const int o = co * 9 + ij;
            const float4* wr = (const float4*)(&W2[o * MID]);
            float s0 = 0.f, s1 = 0.f, s2 = 0.f, s3 = 0.f;
#pragma unroll
            for (int q = 0; q < 8; ++q) {
                const float4 wv = wr[q];
                s0 = fmaf(hm[4 * q + 0], wv.x, s0);
                s1 = fmaf(hm[4 * q + 1], wv.y, s1);
                s2 = fmaf(hm[4 * q + 2], wv.z, s2);
                s3 = fmaf(hm[4 * q + 3], wv.w, s3);
            }
            const float dk = ((s0 + s1) + (s2 + s3)) + b2[o];
            acc = fmaf(dk, p[ij], acc);
        }
        out[baseRgb + (long)co * HW + hw] = acc;
    }
}

extern "C" void kernel_launch(void* const* d_in, const int* in_sizes, int n_in,
                              void* d_out, int out_size, void* d_ws, size_t ws_size,
                              hipStream_t stream) {
    const float* rgb = (const float*)d_in[0];
    const float* ev  = (const float*)d_in[1];
    const float* W1p = (const float*)d_in[2];
    const float* b1p = (const float*)d_in[3];
    const float* W2p = (const float*)d_in[4];
    const float* b2p = (const float*)d_in[5];
    float* out = (float*)d_out;

    const int B = in_sizes[0] / (CRGB * HW);   // = 4
    dim3 grid(B * HH);
    dim3 block(WW);
    hipLaunchKernelGGL(fusion_kernel, grid, block, 0, stream,
                       rgb, ev, W1p, b1p, W2p, b2p, out);
}

// Round 2
// 252.056 us; speedup vs baseline: 1.0175x; 1.0175x over previous
//
#include <hip/hip_runtime.h>

#define CRGB 64
#define CEV  32
#define CIN  96
#define MID  32
#define HH   256
#define WW   256
#define HW   (HH*WW)
#define NO   576   // C_RGB * K * K

typedef _Float16 f16x8 __attribute__((ext_vector_type(8)));
typedef float    f32x4 __attribute__((ext_vector_type(4)));

// d_ws layout (bytes):
//   [0,     36864) : W2h  f16  [õ][m], õ = ij*64 + c  (permuted + converted W2)
//   [36864, 49152) : W1t  f32  [c][m]                 (transposed W1)
//   [49152, 51456) : b2p  f32  [õ]                    (permuted b2)
#define WS_W2H  0
#define WS_W1T  36864
#define WS_B2P  49152

__global__ __launch_bounds__(256) void prep_kernel(
    const float* __restrict__ W1, const float* __restrict__ W2,
    const float* __restrict__ b2, char* __restrict__ ws)
{
    _Float16* W2h = (_Float16*)(ws + WS_W2H);
    float*    W1t = (float*)(ws + WS_W1T);
    float*    b2p = (float*)(ws + WS_B2P);
    const int idx = blockIdx.x * 256 + threadIdx.x;
    if (idx < NO * MID) {                 // 18432
        const int oo = idx >> 5, m = idx & 31;
        const int c = oo & 63, ij = oo >> 6;
        W2h[idx] = (_Float16)W2[(c * 9 + ij) * MID + m];
    }
    if (idx < CIN * MID) {                // 3072
        const int c = idx >> 5, m = idx & 31;
        W1t[idx] = W1[m * CIN + c];
    }
    if (idx < NO) {                       // 576
        const int c = idx & 63, ij = idx >> 6;
        b2p[idx] = b2[c * 9 + ij];
    }
}

// One wave = 32 pixels (two 16-px halves) of one row h.
// Block = 4 waves = 128 consecutive w. Grid = B * H * 2.
__global__ __launch_bounds__(256) void fusion_mfma(
    const float* __restrict__ rgb, const float* __restrict__ ev,
    const float* __restrict__ b1, const char* __restrict__ ws,
    float* __restrict__ out)
{
    const _Float16* W2h = (const _Float16*)(ws + WS_W2H);
    const float*    W1t = (const float*)(ws + WS_W1T);
    const float*    b2p = (const float*)(ws + WS_B2P);

    const int lane = threadIdx.x & 63;
    const int wv   = threadIdx.x >> 6;
    const int l15  = lane & 15;       // pixel within 16-px half (B-frag col)
    const int g    = lane >> 4;       // k-group: m = g*8 + e

    const int b  = blockIdx.x >> 9;
    const int h  = (blockIdx.x >> 1) & 255;
    const int w0 = (blockIdx.x & 1) * 128 + wv * 32;

    const float* rgbP = rgb + (size_t)b * CRGB * HW;
    const float* evP  = ev  + (size_t)b * CEV  * HW;
    float*       outP = out + (size_t)b * CRGB * HW;

    const int wc0 = w0 + l15;         // p=0 column
    const int wc1 = wc0 + 16;         // p=1 column
    const uint32_t row0 = (uint32_t)h * WW;
    const uint32_t ofs0 = row0 + (uint32_t)wc0;
    const uint32_t ofs1 = row0 + (uint32_t)wc1;

    // ---------------- conv1 (fp32 VALU), computed directly in B-frag layout --------
    float hm0[8], hm1[8];
#pragma unroll
    for (int e = 0; e < 8; ++e) { hm0[e] = 0.f; hm1[e] = 0.f; }

#pragma unroll 4
    for (int c = 0; c < CRGB; ++c) {
        const float x0 = rgbP[(uint32_t)c * HW + ofs0];
        const float x1 = rgbP[(uint32_t)c * HW + ofs1];
        const float4 wa = *(const float4*)(W1t + c * MID + g * 8);
        const float4 wb = *(const float4*)(W1t + c * MID + g * 8 + 4);
        const float wr[8] = {wa.x, wa.y, wa.z, wa.w, wb.x, wb.y, wb.z, wb.w};
#pragma unroll
        for (int e = 0; e < 8; ++e) {
            hm0[e] = fmaf(x0, wr[e], hm0[e]);
            hm1[e] = fmaf(x1, wr[e], hm1[e]);
        }
    }
#pragma unroll 4
    for (int c = 0; c < CEV; ++c) {
        const float x0 = evP[(uint32_t)c * HW + ofs0];
        const float x1 = evP[(uint32_t)c * HW + ofs1];
        const float4 wa = *(const float4*)(W1t + (CRGB + c) * MID + g * 8);
        const float4 wb = *(const float4*)(W1t + (CRGB + c) * MID + g * 8 + 4);
        const float wr[8] = {wa.x, wa.y, wa.z, wa.w, wb.x, wb.y, wb.z, wb.w};
#pragma unroll
        for (int e = 0; e < 8; ++e) {
            hm0[e] = fmaf(x0, wr[e], hm0[e]);
            hm1[e] = fmaf(x1, wr[e], hm1[e]);
        }
    }

    // bias + relu + convert to f16 B-fragments
    f16x8 bf0 = {}, bf1 = {};
    {
        const float4 ba = *(const float4*)(b1 + g * 8);
        const float4 bc = *(const float4*)(b1 + g * 8 + 4);
        const float bb[8] = {ba.x, ba.y, ba.z, ba.w, bc.x, bc.y, bc.z, bc.w};
#pragma unroll
        for (int e = 0; e < 8; ++e) {
            float v0 = hm0[e] + bb[e]; v0 = v0 > 0.f ? v0 : 0.f;
            float v1 = hm1[e] + bb[e]; v1 = v1 > 0.f ? v1 : 0.f;
            bf0[e] = (_Float16)v0;
            bf1[e] = (_Float16)v1;
        }
    }

    // ---------------- reflect indices --------------------------------------------
    const int hmm = (h == 0)      ? 1      : h - 1;
    const int hpp = (h == HH - 1) ? HH - 2 : h + 1;
    const uint32_t rowm = (uint32_t)hmm * WW, rowp = (uint32_t)hpp * WW;
    const int wm0 = (wc0 == 0)      ? 1      : wc0 - 1;
    const int wp0 = (wc0 == WW - 1) ? WW - 2 : wc0 + 1;
    const int wm1 = wc1 - 1;                                   // wc1 >= 16, safe
    const int wp1 = (wc1 == WW - 1) ? WW - 2 : wc1 + 1;

    // ---------------- conv2 (MFMA) + apply, fused --------------------------------
    // tile t = ij*4 + cg covers õ in [16t,16t+16); lane's c = cg*16 + g*4 + r,
    // constant over ij -> accumulate output in registers, store once per cg.
    for (int cg = 0; cg < 4; ++cg) {
        uint32_t poff[4];
#pragma unroll
        for (int r = 0; r < 4; ++r)
            poff[r] = (uint32_t)(cg * 16 + g * 4 + r) * (uint32_t)HW;

        f32x4 acc0 = {0.f, 0.f, 0.f, 0.f};
        f32x4 acc1 = {0.f, 0.f, 0.f, 0.f};

#pragma unroll
        for (int ij = 0; ij < 9; ++ij) {
            const int t = ij * 4 + cg;
            const f16x8 afrag = *(const f16x8*)(W2h + (16 * t + l15) * MID + g * 8);
            const f32x4 cinit = *(const f32x4*)(b2p + 16 * t + g * 4);
            const f32x4 d0 = __builtin_amdgcn_mfma_f32_16x16x32_f16(afrag, bf0, cinit, 0, 0, 0);
            const f32x4 d1 = __builtin_amdgcn_mfma_f32_16x16x32_f16(afrag, bf1, cinit, 0, 0, 0);
            const int dh = ij / 3 - 1, dw = ij % 3 - 1;
            const uint32_t rw  = (dh < 0) ? rowm : ((dh > 0) ? rowp : row0);
            const uint32_t bo0 = rw + (uint32_t)((dw < 0) ? wm0 : ((dw > 0) ? wp0 : wc0));
            const uint32_t bo1 = rw + (uint32_t)((dw < 0) ? wm1 : ((dw > 0) ? wp1 : wc1));
#pragma unroll
            for (int r = 0; r < 4; ++r) {
                acc0[r] = fmaf(d0[r], rgbP[poff[r] + bo0], acc0[r]);
                acc1[r] = fmaf(d1[r], rgbP[poff[r] + bo1], acc1[r]);
            }
        }
#pragma unroll
        for (int r = 0; r < 4; ++r) {
            outP[poff[r] + ofs0] = acc0[r];
            outP[poff[r] + ofs1] = acc1[r];
        }
    }
}

extern "C" void kernel_launch(void* const* d_in, const int* in_sizes, int n_in,
                              void* d_out, int out_size, void* d_ws, size_t ws_size,
                              hipStream_t stream) {
    const float* rgb = (const float*)d_in[0];
    const float* ev  = (const float*)d_in[1];
    const float* W1p = (const float*)d_in[2];
    const float* b1p = (const float*)d_in[3];
    const float* W2p = (const float*)d_in[4];
    const float* b2p = (const float*)d_in[5];
    float* out = (float*)d_out;
    char* ws = (char*)d_ws;

    hipLaunchKernelGGL(prep_kernel, dim3(72), dim3(256), 0, stream, W1p, W2p, b2p, ws);

    const int B = in_sizes[0] / (CRGB * HW);   // = 4
    hipLaunchKernelGGL(fusion_mfma, dim3(B * HH * 2), dim3(256), 0, stream,
                       rgb, ev, b1p, ws, out);
}

// Round 3
// 114.905 us; speedup vs baseline: 2.2320x; 2.1936x over previous
//
#include <hip/hip_runtime.h>

#define CRGB 64
#define CEV  32
#define CIN  96
#define MID  32
#define HH   256
#define WW   256
#define HW   (HH*WW)

// tile geometry
#define TW 32
#define TH 8
#define RGBW (TW+2)                 // 34
#define RGBH (TH+2)                 // 10
#define RGBCH 16                    // channels staged per group
#define RGBELEMS (RGBCH*RGBH*RGBW)  // 5440 floats

typedef _Float16 f16x8 __attribute__((ext_vector_type(8)));
typedef float    f32x4 __attribute__((ext_vector_type(4)));

// ws layout (bytes):
//   [0,     36864) : W2h f16, A-frag-linear: idx = (((cg*9+ij)*64 + g*16 + cc)*8 + e), m = g*8+e
//   [36864, 49152) : W1t f32 [c][m]
//   [49152, 51456) : b2p f32 [(cg*9+ij)*16 + cc]
#define WS_W2H 0
#define WS_W1T 36864
#define WS_B2P 49152

__global__ __launch_bounds__(256) void prep_kernel(
    const float* __restrict__ W1, const float* __restrict__ W2,
    const float* __restrict__ b2, char* __restrict__ ws)
{
    _Float16* W2h = (_Float16*)(ws + WS_W2H);
    float*    W1t = (float*)(ws + WS_W1T);
    float*    b2p = (float*)(ws + WS_B2P);
    const int idx = blockIdx.x * 256 + threadIdx.x;
    if (idx < 18432) {
        const int e   = idx & 7;
        const int c16 = idx >> 3;
        const int cc  = c16 & 15;
        const int g   = (c16 >> 4) & 3;
        const int t   = c16 >> 6;        // cg*9+ij, 0..35
        const int ij  = t % 9, cg = t / 9;
        const int m   = g * 8 + e;
        const int ch  = cg * 16 + cc;
        W2h[idx] = (_Float16)W2[(ch * 9 + ij) * MID + m];
    }
    if (idx < CIN * MID) {               // 3072
        W1t[idx] = W1[(idx & 31) * CIN + (idx >> 5)];
    }
    if (idx < 576) {
        const int cc = idx & 15, t = idx >> 4;
        const int ij = t % 9, cg = t / 9;
        b2p[idx] = b2[(cg * 16 + cc) * 9 + ij];
    }
}

// Block = 256 threads (4 waves) = one 8x32 pixel tile, all 64 out channels.
// Grid = 8 col-tiles * 32 row-tiles * B.
__global__ __launch_bounds__(256) void fusion_tiled(
    const float* __restrict__ rgb, const float* __restrict__ ev,
    const float* __restrict__ b1, const char* __restrict__ ws,
    float* __restrict__ out)
{
    __shared__ __align__(16) _Float16 lds_w2h[18432];   // 36864 B
    __shared__ __align__(16) float    lds_rgb[RGBELEMS]; // 21760 B
    __shared__ __align__(16) _Float16 lds_hm[256 * 32];  // 16384 B

    const int tid  = threadIdx.x;
    const int wave = tid >> 6;
    const int lane = tid & 63;
    const int l15  = lane & 15;
    const int g    = lane >> 4;

    const int bx = blockIdx.x;
    const int tc = bx & 7, tr = (bx >> 3) & 31, b = bx >> 8;
    const int px0 = tc * TW, py0 = tr * TH;

    const float* rgbP = rgb + (size_t)b * CRGB * HW;
    const float* evP  = ev  + (size_t)b * CEV  * HW;
    float*       outP = out + (size_t)b * CRGB * HW;

    // ---- stage W2h (1:1 copy, already A-frag-permuted in ws) ----------------
    {
        const uint4* src = (const uint4*)(ws + WS_W2H);
        uint4* dst = (uint4*)lds_w2h;
#pragma unroll
        for (int i = 0; i < 9; ++i) dst[tid + i * 256] = src[tid + i * 256];
    }

    // ---- conv1 for this thread's own pixel (fp32, coalesced lane=px) --------
    {
        const int pxl = tid & 31, pyl = tid >> 5;
        const int gx = px0 + pxl, gy = py0 + pyl;
        const float* W1t = (const float*)(ws + WS_W1T);
        const float* rp = rgbP + (size_t)gy * WW + gx;
        const float* epp = evP + (size_t)gy * WW + gx;

        float hm[MID];
#pragma unroll
        for (int m = 0; m < MID; ++m) hm[m] = 0.f;

#pragma unroll 4
        for (int c = 0; c < CRGB; ++c) {
            const float x = rp[(size_t)c * HW];
#pragma unroll
            for (int m = 0; m < MID; ++m)
                hm[m] = fmaf(x, W1t[c * MID + m], hm[m]);
        }
#pragma unroll 4
        for (int c = 0; c < CEV; ++c) {
            const float x = epp[(size_t)c * HW];
#pragma unroll
            for (int m = 0; m < MID; ++m)
                hm[m] = fmaf(x, W1t[(CRGB + c) * MID + m], hm[m]);
        }

        // bias + relu + pack to f16 B-frag chunks; XOR-g swizzled LDS write
        f16x8* hmv = (f16x8*)lds_hm;
#pragma unroll
        for (int g2 = 0; g2 < 4; ++g2) {
            f16x8 v;
#pragma unroll
            for (int e = 0; e < 8; ++e) {
                const float tv = hm[g2 * 8 + e] + b1[g2 * 8 + e];
                v[e] = (_Float16)(tv > 0.f ? tv : 0.f);
            }
            hmv[g2 * 256 + (tid ^ g2)] = v;
        }
    }

    const float* b2p = (const float*)(ws + WS_B2P);

    // ---- main loop over 4 channel-groups ------------------------------------
    for (int cg = 0; cg < 4; ++cg) {
        if (cg) __syncthreads();   // previous compute done reading lds_rgb

        // stage rgb channels [cg*16, cg*16+16) with halo + reflect
        {
            const float* basep = rgbP + (size_t)cg * RGBCH * HW;
#pragma unroll
            for (int i = 0; i < 22; ++i) {
                const int e = tid + i * 256;
                if (e < RGBELEMS) {
                    const int cc  = e / (RGBH * RGBW);
                    const int rem = e - cc * (RGBH * RGBW);
                    const int row = rem / RGBW;
                    const int col = rem - row * RGBW;
                    int gyy = py0 - 1 + row; gyy = gyy < 0 ? 1 : (gyy > HH - 1 ? HH - 2 : gyy);
                    int gxx = px0 - 1 + col; gxx = gxx < 0 ? 1 : (gxx > WW - 1 ? WW - 2 : gxx);
                    lds_rgb[e] = basep[(size_t)cc * HW + gyy * WW + gxx];
                }
            }
        }
        __syncthreads();           // rgb staged (also covers w2h/hm at cg==0)

        // A-fragments for this cg: 9 taps, held in registers
        f16x8 af[9];
#pragma unroll
        for (int ij = 0; ij < 9; ++ij)
            af[ij] = ((const f16x8*)lds_w2h)[(cg * 9 + ij) * 64 + g * 16 + l15];

        // wave's 4 px-subtiles: rows {2*wave, 2*wave+1} x halves {0,1}
#pragma unroll
        for (int st = 0; st < 4; ++st) {
            const int row_l = wave * 2 + (st & 1);
            const int half  = st >> 1;
            const int pxl2  = half * 16 + l15;
            const int p     = row_l * 32 + pxl2;

            const f16x8 bf = ((const f16x8*)lds_hm)[g * 256 + (p ^ g)];

            float acc0 = 0.f, acc1 = 0.f, acc2 = 0.f, acc3 = 0.f;
#pragma unroll
            for (int ij = 0; ij < 9; ++ij) {
                const int dh = ij / 3, dw = ij % 3;
                const f32x4 ci = *(const f32x4*)(b2p + (cg * 9 + ij) * 16 + g * 4);
                const f32x4 d = __builtin_amdgcn_mfma_f32_16x16x32_f16(af[ij], bf, ci, 0, 0, 0);
                const int pb = (row_l + dh) * RGBW + pxl2 + dw;
                acc0 = fmaf(d[0], lds_rgb[(g * 4 + 0) * (RGBH * RGBW) + pb], acc0);
                acc1 = fmaf(d[1], lds_rgb[(g * 4 + 1) * (RGBH * RGBW) + pb], acc1);
                acc2 = fmaf(d[2], lds_rgb[(g * 4 + 2) * (RGBH * RGBW) + pb], acc2);
                acc3 = fmaf(d[3], lds_rgb[(g * 4 + 3) * (RGBH * RGBW) + pb], acc3);
            }
            float* op = outP + (size_t)(cg * 16 + g * 4) * HW + (size_t)(py0 + row_l) * WW + px0 + pxl2;
            op[0]      = acc0;
            op[HW]     = acc1;
            op[2 * HW] = acc2;
            op[3 * HW] = acc3;
        }
    }
}

extern "C" void kernel_launch(void* const* d_in, const int* in_sizes, int n_in,
                              void* d_out, int out_size, void* d_ws, size_t ws_size,
                              hipStream_t stream) {
    const float* rgb = (const float*)d_in[0];
    const float* ev  = (const float*)d_in[1];
    const float* W1p = (const float*)d_in[2];
    const float* b1p = (const float*)d_in[3];
    const float* W2p = (const float*)d_in[4];
    const float* b2p = (const float*)d_in[5];
    float* out = (float*)d_out;
    char* ws = (char*)d_ws;

    hipLaunchKernelGGL(prep_kernel, dim3(72), dim3(256), 0, stream, W1p, W2p, b2p, ws);

    const int B = in_sizes[0] / (CRGB * HW);   // = 4
    hipLaunchKernelGGL(fusion_tiled, dim3(B * 256), dim3(256), 0, stream,
                       rgb, ev, b1p, ws, out);
}

// Round 4
// 98.335 us; speedup vs baseline: 2.6081x; 1.1685x over previous
//
#include <hip/hip_runtime.h>

#define CRGB 64
#define CEV  32
#define CIN  96
#define MID  32
#define HH   256
#define WW   256
#define HW   (HH*WW)

// tile geometry
#define TW 32
#define TH 8
#define RGBW (TW+2)                 // 34
#define RGBH (TH+2)                 // 10
#define RGBCH 16                    // channels staged per group
#define RGBELEMS (RGBCH*RGBH*RGBW)  // 5440

typedef _Float16 f16x8 __attribute__((ext_vector_type(8)));
typedef float    f32x4 __attribute__((ext_vector_type(4)));

// ws layout (bytes):
//   [0,     36864) : W2h f16, A-frag-linear: idx = (((cg*9+ij)*64 + g*16 + cc)*8 + e), m = g*8+e
//   [36864, 49152) : W1t f32 [c][m]
//   [49152, 51456) : b2p f32 [(cg*9+ij)*16 + cc]
#define WS_W2H 0
#define WS_W1T 36864
#define WS_B2P 49152

__global__ __launch_bounds__(256) void prep_kernel(
    const float* __restrict__ W1, const float* __restrict__ W2,
    const float* __restrict__ b2, char* __restrict__ ws)
{
    _Float16* W2h = (_Float16*)(ws + WS_W2H);
    float*    W1t = (float*)(ws + WS_W1T);
    float*    b2p = (float*)(ws + WS_B2P);
    const int idx = blockIdx.x * 256 + threadIdx.x;
    if (idx < 18432) {
        const int e   = idx & 7;
        const int c16 = idx >> 3;
        const int cc  = c16 & 15;
        const int g   = (c16 >> 4) & 3;
        const int t   = c16 >> 6;        // cg*9+ij, 0..35
        const int ij  = t % 9, cg = t / 9;
        const int m   = g * 8 + e;
        const int ch  = cg * 16 + cc;
        W2h[idx] = (_Float16)W2[(ch * 9 + ij) * MID + m];
    }
    if (idx < CIN * MID) {               // 3072
        W1t[idx] = W1[(idx & 31) * CIN + (idx >> 5)];
    }
    if (idx < 576) {
        const int cc = idx & 15, t = idx >> 4;
        const int ij = t % 9, cg = t / 9;
        b2p[idx] = b2[(cg * 16 + cc) * 9 + ij];
    }
}

// Block = 256 threads (4 waves) = one 8x32 pixel tile, all 64 out channels.
// Grid = 8 col-tiles * 32 row-tiles * B.
__global__ __launch_bounds__(256, 4) void fusion_tiled(
    const float* __restrict__ rgb, const float* __restrict__ ev,
    const float* __restrict__ b1, const char* __restrict__ ws,
    float* __restrict__ out)
{
    __shared__ __align__(16) _Float16 lds_rgb[RGBELEMS];  // 10880 B
    __shared__ __align__(16) _Float16 lds_hm[256 * 32];   // 16384 B

    const int tid  = threadIdx.x;
    const int wave = tid >> 6;
    const int lane = tid & 63;
    const int l15  = lane & 15;
    const int g    = lane >> 4;

    const int bx = blockIdx.x;
    const int tc = bx & 7, tr = (bx >> 3) & 31, b = bx >> 8;
    const int px0 = tc * TW, py0 = tr * TH;

    const float* rgbP = rgb + (size_t)b * CRGB * HW;
    const float* evP  = ev  + (size_t)b * CEV  * HW;
    float*       outP = out + (size_t)b * CRGB * HW;

    // ---- conv1 for this thread's own pixel (fp32, coalesced lane=px) --------
    {
        const int pxl = tid & 31, pyl = tid >> 5;
        const int gx = px0 + pxl, gy = py0 + pyl;
        const float* W1t = (const float*)(ws + WS_W1T);
        const float* rp = rgbP + (size_t)gy * WW + gx;
        const float* epp = evP + (size_t)gy * WW + gx;

        float hm[MID];
#pragma unroll
        for (int m = 0; m < MID; ++m) hm[m] = 0.f;

        // batched loads: 8 independent VMEM in flight per round
        for (int c0 = 0; c0 < CRGB; c0 += 8) {
            float xs[8];
#pragma unroll
            for (int j = 0; j < 8; ++j) xs[j] = rp[(size_t)(c0 + j) * HW];
#pragma unroll
            for (int j = 0; j < 8; ++j)
#pragma unroll
                for (int m = 0; m < MID; ++m)
                    hm[m] = fmaf(xs[j], W1t[(c0 + j) * MID + m], hm[m]);
        }
        for (int c0 = 0; c0 < CEV; c0 += 8) {
            float xs[8];
#pragma unroll
            for (int j = 0; j < 8; ++j) xs[j] = epp[(size_t)(c0 + j) * HW];
#pragma unroll
            for (int j = 0; j < 8; ++j)
#pragma unroll
                for (int m = 0; m < MID; ++m)
                    hm[m] = fmaf(xs[j], W1t[(CRGB + c0 + j) * MID + m], hm[m]);
        }

        // bias + relu + pack to f16 B-frag chunks; XOR-g swizzled LDS write
        f16x8* hmv = (f16x8*)lds_hm;
#pragma unroll
        for (int g2 = 0; g2 < 4; ++g2) {
            f16x8 v;
#pragma unroll
            for (int e = 0; e < 8; ++e) {
                const float tv = hm[g2 * 8 + e] + b1[g2 * 8 + e];
                v[e] = (_Float16)(tv > 0.f ? tv : 0.f);
            }
            hmv[g2 * 256 + (tid ^ g2)] = v;
        }
    }

    const float*    b2p = (const float*)(ws + WS_B2P);
    const _Float16* W2h = (const _Float16*)(ws + WS_W2H);

    // ---- main loop over 4 channel-groups ------------------------------------
    for (int cg = 0; cg < 4; ++cg) {
        if (cg) __syncthreads();   // previous compute done reading lds_rgb

        // stage rgb channels [cg*16, cg*16+16) with halo + reflect, as f16
        {
            const float* basep = rgbP + (size_t)cg * RGBCH * HW;
#pragma unroll
            for (int i = 0; i < 22; ++i) {
                const int e = tid + i * 256;
                if (e < RGBELEMS) {
                    const int cc  = e / (RGBH * RGBW);
                    const int rem = e - cc * (RGBH * RGBW);
                    const int row = rem / RGBW;
                    const int col = rem - row * RGBW;
                    int gyy = py0 - 1 + row; gyy = gyy < 0 ? 1 : (gyy > HH - 1 ? HH - 2 : gyy);
                    int gxx = px0 - 1 + col; gxx = gxx < 0 ? 1 : (gxx > WW - 1 ? WW - 2 : gxx);
                    lds_rgb[e] = (_Float16)basep[(size_t)cc * HW + gyy * WW + gxx];
                }
            }
        }
        __syncthreads();           // rgb staged (also covers hm at cg==0)

        // A-fragments for this cg: 9 taps, from global (L2-hot, coalesced 1KB/inst)
        f16x8 af[9];
#pragma unroll
        for (int ij = 0; ij < 9; ++ij)
            af[ij] = ((const f16x8*)W2h)[(cg * 9 + ij) * 64 + g * 16 + l15];

        // wave's 4 px-subtiles: rows {2*wave, 2*wave+1} x halves {0,1}
#pragma unroll
        for (int st = 0; st < 4; ++st) {
            const int row_l = wave * 2 + (st & 1);
            const int half  = st >> 1;
            const int pxl2  = half * 16 + l15;
            const int p     = row_l * 32 + pxl2;

            const f16x8 bf = ((const f16x8*)lds_hm)[g * 256 + (p ^ g)];

            float acc0 = 0.f, acc1 = 0.f, acc2 = 0.f, acc3 = 0.f;
#pragma unroll
            for (int ij = 0; ij < 9; ++ij) {
                const int dh = ij / 3, dw = ij % 3;
                const f32x4 ci = *(const f32x4*)(b2p + (cg * 9 + ij) * 16 + g * 4);
                const f32x4 d = __builtin_amdgcn_mfma_f32_16x16x32_f16(af[ij], bf, ci, 0, 0, 0);
                const int pb = (row_l + dh) * RGBW + pxl2 + dw;
                acc0 = fmaf(d[0], (float)lds_rgb[(g * 4 + 0) * (RGBH * RGBW) + pb], acc0);
                acc1 = fmaf(d[1], (float)lds_rgb[(g * 4 + 1) * (RGBH * RGBW) + pb], acc1);
                acc2 = fmaf(d[2], (float)lds_rgb[(g * 4 + 2) * (RGBH * RGBW) + pb], acc2);
                acc3 = fmaf(d[3], (float)lds_rgb[(g * 4 + 3) * (RGBH * RGBW) + pb], acc3);
            }
            float* op = outP + (size_t)(cg * 16 + g * 4) * HW + (size_t)(py0 + row_l) * WW + px0 + pxl2;
            op[0]      = acc0;
            op[HW]     = acc1;
            op[2 * HW] = acc2;
            op[3 * HW] = acc3;
        }
    }
}

extern "C" void kernel_launch(void* const* d_in, const int* in_sizes, int n_in,
                              void* d_out, int out_size, void* d_ws, size_t ws_size,
                              hipStream_t stream) {
    const float* rgb = (const float*)d_in[0];
    const float* ev  = (const float*)d_in[1];
    const float* W1p = (const float*)d_in[2];
    const float* b1p = (const float*)d_in[3];
    const float* W2p = (const float*)d_in[4];
    const float* b2p = (const float*)d_in[5];
    float* out = (float*)d_out;
    char* ws = (char*)d_ws;

    hipLaunchKernelGGL(prep_kernel, dim3(72), dim3(256), 0, stream, W1p, W2p, b2p, ws);

    const int B = in_sizes[0] / (CRGB * HW);   // = 4
    hipLaunchKernelGGL(fusion_tiled, dim3(B * 256), dim3(256), 0, stream,
                       rgb, ev, b1p, ws, out);
}

// Round 5
// 66.140 us; speedup vs baseline: 3.8777x; 1.4868x over previous
//
#include <hip/hip_runtime.h>

#define CRGB 64
#define CEV  32
#define CIN  96
#define MID  32
#define HH   256
#define WW   256
#define HW   (HH*WW)

// tile geometry: block = 512 threads = 16x32 pixels, halo tile 18x34
#define TLH 16
#define TLW 32
#define SRH 18
#define SRW 34
#define SPX (SRH*SRW)   // 612 pixels, 64 ch f16 = 78336 B LDS

typedef _Float16 f16x8 __attribute__((ext_vector_type(8)));
typedef _Float16 f16x4 __attribute__((ext_vector_type(4)));
typedef float    f32x4 __attribute__((ext_vector_type(4)));

// ws layout (bytes):
//   [0,     36864) : W2f f16 A-frag-linear, k-dim permuted: kappa = g*8+mh*4+r <-> m = mh*16+g*4+r
//   [36864, 43008) : W1f f16 A-frag-linear (natural k-order)
//   [43008, 45312) : b2p f32 [(cg*9+ij)*16 + cc]
#define WS_W2F 0
#define WS_W1F 36864
#define WS_B2P 43008

__global__ __launch_bounds__(256) void prep_kernel(
    const float* __restrict__ W1, const float* __restrict__ W2,
    const float* __restrict__ b2, char* __restrict__ ws)
{
    _Float16* W2f = (_Float16*)(ws + WS_W2F);
    _Float16* W1f = (_Float16*)(ws + WS_W1F);
    float*    b2p = (float*)(ws + WS_B2P);
    const int idx = blockIdx.x * 256 + threadIdx.x;
    if (idx < 18432) {
        const int e   = idx & 7;
        const int ln  = (idx >> 3) & 63;
        const int t   = idx >> 9;             // cg*9+ij, 0..35
        const int ij  = t % 9, cg = t / 9;
        const int c   = cg * 16 + (ln & 15);  // A row = out channel within cg
        const int kap = (ln >> 4) * 8 + e;    // kappa
        const int m   = ((kap >> 2) & 1) * 16 + (kap >> 3) * 4 + (kap & 3);
        W2f[idx] = (_Float16)W2[(c * 9 + ij) * MID + m];
    }
    if (idx < 3072) {
        const int e  = idx & 7;
        const int ln = (idx >> 3) & 63;
        const int t  = idx >> 9;              // ks*2+mh, 0..5
        const int ks = t >> 1, mh = t & 1;
        const int m  = mh * 16 + (ln & 15);
        const int k  = ks * 32 + (ln >> 4) * 8 + e;
        W1f[idx] = (_Float16)W1[m * CIN + k];
    }
    if (idx < 576) {
        const int cc = idx & 15;
        const int t  = idx >> 4;
        const int ij = t % 9, cg = t / 9;
        b2p[idx] = b2[(cg * 16 + cc) * 9 + ij];
    }
}

// Block = 512 threads (8 waves) = 16x32 px tile, all 64 out channels.
// Wave w owns rows {2w, 2w+1}. One barrier total. LDS swizzle: 16B chunk
// q of pixel p stored at unit p*8 + (q ^ (p&7)).
__global__ __launch_bounds__(512, 4) void fusion_mfma2(
    const float* __restrict__ rgb, const float* __restrict__ ev,
    const float* __restrict__ b1, const char* __restrict__ ws,
    float* __restrict__ out)
{
    __shared__ __align__(16) _Float16 srgb[SPX * 64];   // 78336 B

    const int tid  = threadIdx.x;
    const int wave = tid >> 6;
    const int lane = tid & 63;
    const int l15  = lane & 15;
    const int g    = lane >> 4;

    const int bx = blockIdx.x;
    const int tc = bx & 7, tr = (bx >> 3) & 15, b = bx >> 7;
    const int px0 = tc * TLW, py0 = tr * TLH;

    const float* rgbP = rgb + (size_t)b * CRGB * HW;
    const float* evP  = ev  + (size_t)b * CEV  * HW;
    float*       outP = out + (size_t)b * CRGB * HW;

    const _Float16* W2f = (const _Float16*)(ws + WS_W2F);
    const _Float16* W1f = (const _Float16*)(ws + WS_W1F);
    const float*    b2p = (const float*)(ws + WS_B2P);

    // ---- stage full rgb halo tile (64 ch, reflect) as f16, swizzled ---------
    f16x8* sv = (f16x8*)srgb;
    for (int p = tid; p < SPX; p += 512) {
        const int row = p / SRW;
        const int col = p - row * SRW;
        int gy = py0 - 1 + row; gy = gy < 0 ? 1 : (gy > HH - 1 ? HH - 2 : gy);
        int gx = px0 - 1 + col; gx = gx < 0 ? 1 : (gx > WW - 1 ? WW - 2 : gx);
        const float* src = rgbP + (size_t)gy * WW + gx;
        const int pb = p * 8, ps = p & 7;
#pragma unroll
        for (int q = 0; q < 8; ++q) {
            f16x8 v;
#pragma unroll
            for (int e = 0; e < 8; ++e)
                v[e] = (_Float16)src[(size_t)(q * 8 + e) * HW];
            sv[pb + (q ^ ps)] = v;
        }
    }

    // conv1 A-frags + biases (independent of staging)
    f16x8 a1[6];
#pragma unroll
    for (int t = 0; t < 6; ++t)
        a1[t] = ((const f16x8*)W1f)[t * 64 + lane];
    const f32x4 b1v0 = *(const f32x4*)(b1 + g * 4);
    const f32x4 b1v1 = *(const f32x4*)(b1 + 16 + g * 4);

    __syncthreads();

    // ---- conv1 via MFMA: produce conv2 B-frags entirely in registers --------
    // st: row_l = 2*wave + (st&1), col = (st>>1)*16 + l15
    f16x8 bfr[4];
#pragma unroll
    for (int st = 0; st < 4; ++st) {
        const int row_l = wave * 2 + (st & 1);
        const int col   = (st >> 1) * 16 + l15;
        const int pt    = (row_l + 1) * SRW + col + 1;
        const f16x8 bk0 = sv[pt * 8 + ( g      ^ (pt & 7))];
        const f16x8 bk1 = sv[pt * 8 + ((4 + g) ^ (pt & 7))];
        const float* esrc = evP + (size_t)(py0 + row_l) * WW + (px0 + col);
        f16x8 bk2;
#pragma unroll
        for (int e = 0; e < 8; ++e)
            bk2[e] = (_Float16)esrc[(size_t)(g * 8 + e) * HW];
        f32x4 d0 = {0.f, 0.f, 0.f, 0.f}, d1 = {0.f, 0.f, 0.f, 0.f};
        d0 = __builtin_amdgcn_mfma_f32_16x16x32_f16(a1[0], bk0, d0, 0, 0, 0);
        d1 = __builtin_amdgcn_mfma_f32_16x16x32_f16(a1[1], bk0, d1, 0, 0, 0);
        d0 = __builtin_amdgcn_mfma_f32_16x16x32_f16(a1[2], bk1, d0, 0, 0, 0);
        d1 = __builtin_amdgcn_mfma_f32_16x16x32_f16(a1[3], bk1, d1, 0, 0, 0);
        d0 = __builtin_amdgcn_mfma_f32_16x16x32_f16(a1[4], bk2, d0, 0, 0, 0);
        d1 = __builtin_amdgcn_mfma_f32_16x16x32_f16(a1[5], bk2, d1, 0, 0, 0);
        // bias + relu + pack: e = mh*4+r -> kappa = g*8+mh*4+r (matches W2f perm)
        f16x8 bf;
#pragma unroll
        for (int r = 0; r < 4; ++r) {
            float v0 = d0[r] + b1v0[r]; v0 = v0 > 0.f ? v0 : 0.f;
            float v1 = d1[r] + b1v1[r]; v1 = v1 > 0.f ? v1 : 0.f;
            bf[r]     = (_Float16)v0;
            bf[4 + r] = (_Float16)v1;
        }
        bfr[st] = bf;
    }

    // ---- conv2 (MFMA, bias via C-init) + apply from LDS ---------------------
    for (int cg = 0; cg < 4; ++cg) {
        f16x8 a2[9];
        f32x4 ci[9];
#pragma unroll
        for (int ij = 0; ij < 9; ++ij) {
            a2[ij] = ((const f16x8*)W2f)[(cg * 9 + ij) * 64 + lane];
            ci[ij] = *(const f32x4*)(b2p + (cg * 9 + ij) * 16 + g * 4);
        }
        const int qs  = cg * 2 + (g >> 1);   // 16B chunk of this lane's ch-quad
        const int sub = g & 1;               // 8B half within chunk
#pragma unroll
        for (int st = 0; st < 4; ++st) {
            const int row_l = wave * 2 + (st & 1);
            const int col   = (st >> 1) * 16 + l15;
            float acc0 = 0.f, acc1 = 0.f, acc2 = 0.f, acc3 = 0.f;
#pragma unroll
            for (int ij = 0; ij < 9; ++ij) {
                const f32x4 d = __builtin_amdgcn_mfma_f32_16x16x32_f16(a2[ij], bfr[st], ci[ij], 0, 0, 0);
                const int pt = (row_l + ij / 3) * SRW + col + (ij % 3);
                const f16x4 pv = ((const f16x4*)srgb)[(pt * 8 + (qs ^ (pt & 7))) * 2 + sub];
                acc0 = fmaf(d[0], (float)pv[0], acc0);
                acc1 = fmaf(d[1], (float)pv[1], acc1);
                acc2 = fmaf(d[2], (float)pv[2], acc2);
                acc3 = fmaf(d[3], (float)pv[3], acc3);
            }
            float* op = outP + (size_t)(cg * 16 + g * 4) * HW
                             + (size_t)(py0 + row_l) * WW + (px0 + col);
            op[0]      = acc0;
            op[HW]     = acc1;
            op[2 * HW] = acc2;
            op[3 * HW] = acc3;
        }
    }
}

extern "C" void kernel_launch(void* const* d_in, const int* in_sizes, int n_in,
                              void* d_out, int out_size, void* d_ws, size_t ws_size,
                              hipStream_t stream) {
    const float* rgb = (const float*)d_in[0];
    const float* ev  = (const float*)d_in[1];
    const float* W1p = (const float*)d_in[2];
    const float* b1p = (const float*)d_in[3];
    const float* W2p = (const float*)d_in[4];
    const float* b2p = (const float*)d_in[5];
    float* out = (float*)d_out;
    char* ws = (char*)d_ws;

    hipLaunchKernelGGL(prep_kernel, dim3(72), dim3(256), 0, stream, W1p, W2p, b2p, ws);

    const int B = in_sizes[0] / (CRGB * HW);   // = 4
    hipLaunchKernelGGL(fusion_mfma2, dim3(B * 128), dim3(512), 0, stream,
                       rgb, ev, b1p, ws, out);
}